// Round 2
// baseline (499.457 us; speedup 1.0000x reference)
//
#include <hip/hip_runtime.h>

#define BATCH 8
#define HH 2048
#define WW 2048
#define NPIX (HH*WW)
#define TOPK 8192
#define NB 16384
#define PEAK_CAP 196608
#define FCHUNK 8192
#define LBINS 2048
#define LO_BIN (NB - LBINS)
#define CAND_CAP 16384

// NMS tile geometry: 256x32 outputs per 512-thread block
#define NMS_TW 256
#define NMS_TH 32
#define NMS_ROWS 36            // 32 + 4 halo rows
#define NMS_RQ 66              // float4 per tile row (264 floats >= 256+8 halo)
#define NMS_F4 (NMS_ROWS * NMS_RQ)   // 2376 float4 = 38016 B
#define LBUF_CAP 768

// workspace byte offsets (HIST->SA->FILL->counters contiguous for one memset)
#define OFF_PEAKS  0ull
#define OFF_CANDS  (OFF_PEAKS + (size_t)BATCH*PEAK_CAP*8ull)
#define OFF_HIST   (OFF_CANDS + (size_t)BATCH*CAND_CAP*8ull)
#define OFF_SA     (OFF_HIST  + (size_t)BATCH*NB*4ull)
#define OFF_FILL   (OFF_SA    + (size_t)BATCH*NB*4ull)
#define OFF_PCOUNT (OFF_FILL  + (size_t)BATCH*NB*4ull)
#define OFF_NCAND  (OFF_PCOUNT + 64ull)
#define OFF_BSTAR  (OFF_NCAND + 64ull)
#define OFF_END    (OFF_PCOUNT + 192ull)

__device__ __forceinline__ int bucket_of(float v) {
    int bk = (int)(v * 16384.0f);
    if (bk > NB - 1) bk = NB - 1;
    if (bk < 0) bk = 0;
    return bk;
}

// ---------------- K1: NMS via LDS-staged tile (register staging) ----------------
// Block 512 threads -> 256x32 outputs. Stage 36x264-float tile (38 KB) with
// ~5 independent float4 loads/thread (all in flight), then conflict-free
// ds_read_b128 compute. Builds the value histogram during the peak drain
// (replaces the old k_hist kernel).
__global__ __launch_bounds__(512) void k_nms(
    const float* __restrict__ scores,
    unsigned long long* __restrict__ peaks,
    unsigned int* __restrict__ pcount,
    unsigned int* __restrict__ hist)
{
    const int b = blockIdx.z;
    const int tid = threadIdx.x;
    const int x0 = blockIdx.x * NMS_TW;
    const int y0 = blockIdx.y * NMS_TH;
    const float4* imgq = (const float4*)(scores + (size_t)b * NPIX);
    const int q0 = x0 >> 2;

    __shared__ float4 tile[NMS_F4];                // 38016 B
    __shared__ unsigned long long lbuf[LBUF_CAP];  // 6144 B
    __shared__ unsigned int lcnt;
    __shared__ unsigned int lbase;
    if (tid == 0) lcnt = 0;

    // ---- stage: rows y0-2 .. y0+33, float4 cols q0-1 .. q0+64 (clamped) ----
    // Pass 1: issue all global loads into registers (static indices -> VGPRs).
    float4 stg[5];
#pragma unroll
    for (int k = 0; k < 5; ++k) {
        const int f = tid + k * 512;
        if (f < NMS_F4) {
            const int r = f / NMS_RQ;
            const int c = f - r * NMS_RQ;
            int gy = y0 - 2 + r;
            gy = gy < 0 ? 0 : (gy > HH - 1 ? HH - 1 : gy);
            int gq = q0 - 1 + c;
            gq = gq < 0 ? 0 : (gq > WW / 4 - 1 ? WW / 4 - 1 : gq);
            stg[k] = imgq[(size_t)gy * (WW / 4) + gq];
        }
    }
    // Pass 2: LDS writes.
#pragma unroll
    for (int k = 0; k < 5; ++k) {
        const int f = tid + k * 512;
        if (f < NMS_F4) tile[f] = stg[k];
    }
    __syncthreads();

    // ---- compute: wave = 64 lanes spanning one row -> contiguous LDS reads ----
    const int tx = tid & 63;       // 4-col group
    const int ty = tid >> 6;       // 4-row group (uniform within a wave)
    const int lr0 = ty << 2;

    float hm[8][4];
    float c4[4][4];
#pragma unroll
    for (int j = 0; j < 8; ++j) {
        const float4 A = tile[(lr0 + j) * NMS_RQ + tx];
        const float4 B = tile[(lr0 + j) * NMS_RQ + tx + 1];
        const float4 C = tile[(lr0 + j) * NMS_RQ + tx + 2];
        const float v[12] = {A.x, A.y, A.z, A.w, B.x, B.y, B.z, B.w,
                             C.x, C.y, C.z, C.w};
        float aa[8];
#pragma unroll
        for (int k = 0; k < 8; ++k) aa[k] = fmaxf(v[k + 2], v[k + 3]);
#pragma unroll
        for (int i = 0; i < 4; ++i)
            hm[j][i] = fmaxf(fmaxf(aa[i], aa[i + 2]), v[i + 6]);
        if (j >= 2 && j <= 5) {
#pragma unroll
            for (int i = 0; i < 4; ++i) c4[j - 2][i] = v[i + 4];
        }
    }

#pragma unroll
    for (int rr = 0; rr < 4; ++rr) {
        const int oy = y0 + lr0 + rr;
        const bool yok = (oy >= 2) && (oy <= HH - 3);
#pragma unroll
        for (int i = 0; i < 4; ++i) {
            const float vm = fmaxf(fmaxf(fmaxf(hm[rr][i], hm[rr + 1][i]),
                                         fmaxf(hm[rr + 2][i], hm[rr + 3][i])),
                                   hm[rr + 4][i]);
            const float cv = c4[rr][i];
            const int col = x0 + tx * 4 + i;
            if (yok && col >= 2 && col <= WW - 3 && cv == vm) {
                unsigned int pos = atomicAdd(&lcnt, 1u);
                if (pos < (unsigned int)LBUF_CAP) {
                    unsigned int idx = (unsigned int)(oy * WW + col);
                    lbuf[pos] = ((unsigned long long)__float_as_uint(cv) << 32) |
                                (unsigned long long)(~idx);
                }
            }
        }
    }
    __syncthreads();

    unsigned int cnt = lcnt;
    if (cnt > (unsigned int)LBUF_CAP) cnt = LBUF_CAP;
    if (tid == 0) lbase = atomicAdd(&pcount[b], cnt);
    __syncthreads();
    const unsigned int gbase = lbase;
    for (unsigned int s = tid; s < cnt; s += 512) {
        const unsigned long long key = lbuf[s];
        const unsigned int gpos = gbase + s;
        if (gpos < PEAK_CAP) peaks[(size_t)b * PEAK_CAP + gpos] = key;
        const float v = __uint_as_float((unsigned int)(key >> 32));
        atomicAdd(&hist[(size_t)b * NB + bucket_of(v)], 1u);   // fused k_hist
    }
}

// ---------------- K2: suffix scan over global hist ----------------
// grid: (8), block 256. Histogram now comes straight from k_nms atomics.
__global__ __launch_bounds__(256) void k_scan(
    const unsigned int* __restrict__ hist,
    unsigned int* __restrict__ SA,
    unsigned int* __restrict__ ncand,
    unsigned int* __restrict__ bstar)
{
    const int b = blockIdx.x;
    unsigned int* sab = SA + b * NB;
    const int t = threadIdx.x;

    __shared__ unsigned int h[NB / 2];   // packed lo | hi<<16, 32 KB
    __shared__ unsigned int ps[256];
    __shared__ int bmax;

    const uint2* hb = (const uint2*)(hist + (size_t)b * NB);
    for (int w = t; w < NB / 2; w += 256) {
        const uint2 p = hb[w];
        h[w] = p.x | (p.y << 16);        // counts < 65536
    }
    __syncthreads();

    // per-thread 64-bin total; rotated index -> conflict-free LDS
    unsigned int sum = 0;
    for (int kk = 0; kk < 32; ++kk) {
        const int k = (kk + t) & 31;
        const unsigned int p = h[t * 32 + k];
        sum += (p & 0xFFFFu) + (p >> 16);
    }
    ps[t] = sum;
    __syncthreads();
    for (int off = 1; off < 256; off <<= 1) {
        unsigned int v = (t + off < 256) ? ps[t + off] : 0u;
        __syncthreads();
        ps[t] += v;
        __syncthreads();
    }
    unsigned int run = ps[t] - sum;  // strictly above this thread's chunk
    int bst_local = -1;
    for (int i = 63; i >= 0; --i) {
        const int bin = t * 64 + i;
        const unsigned int w = h[t * 32 + (i >> 1)];
        const unsigned int hv = (i & 1) ? (w >> 16) : (w & 0xFFFFu);
        sab[bin] = run;
        if (run + hv >= TOPK && bst_local < 0) bst_local = bin;
        run += hv;
    }
    if (t == 0) bmax = -1;
    __syncthreads();
    if (bst_local >= 0) atomicMax(&bmax, bst_local);
    __syncthreads();
    if (t == 0) {
        const int Bs = bmax < 0 ? 0 : bmax;
        bstar[b] = (unsigned int)Bs;
        const unsigned int w = h[Bs >> 1];
        const unsigned int hv = (Bs & 1) ? (w >> 16) : (w & 0xFFFFu);
        unsigned int nc = sab[Bs] + hv;
        if (nc > CAND_CAP) nc = CAND_CAP;
        ncand[b] = nc;
    }
}

// ---------------- K3: filter -> bucket-grouped cands, aggregated atomics ----------------
__global__ __launch_bounds__(256) void k_filter(
    const unsigned long long* __restrict__ peaks,
    const unsigned int* __restrict__ pcount,
    const unsigned int* __restrict__ bstar,
    const unsigned int* __restrict__ SA,
    unsigned int* __restrict__ fill,
    unsigned long long* __restrict__ cands)
{
    const int b = blockIdx.y;
    unsigned int n = pcount[b];
    if (n > PEAK_CAP) n = PEAK_CAP;
    const unsigned int base = blockIdx.x * FCHUNK;
    if (base >= n) return;
    const unsigned int end = (base + FCHUNK < n) ? base + FCHUNK : n;
    const unsigned int bs = bstar[b];
    const unsigned long long* pb = peaks + (size_t)b * PEAK_CAP;
    unsigned long long* cb = cands + (size_t)b * CAND_CAP;

    __shared__ unsigned int cnt[LBINS];
    __shared__ unsigned int off[LBINS];
    for (int j = threadIdx.x; j < LBINS; j += 256) { cnt[j] = 0u; off[j] = 0u; }
    __syncthreads();

    for (unsigned int i = base + threadIdx.x; i < end; i += 256) {
        const unsigned long long key = pb[i];
        const float v = __uint_as_float((unsigned int)(key >> 32));
        const int bk = bucket_of(v);
        if ((unsigned int)bk < bs) continue;
        if (bk >= LO_BIN) {
            atomicAdd(&cnt[bk - LO_BIN], 1u);
        } else {
            unsigned int pos = SA[b * NB + bk] + atomicAdd(&fill[b * NB + bk], 1u);
            if (pos < CAND_CAP) cb[pos] = key;
        }
    }
    __syncthreads();

    for (int j = threadIdx.x; j < LBINS; j += 256) {
        const unsigned int c = cnt[j];
        if (c) cnt[j] = atomicAdd(&fill[b * NB + LO_BIN + j], c);
    }
    __syncthreads();

    for (unsigned int i = base + threadIdx.x; i < end; i += 256) {
        const unsigned long long key = pb[i];
        const float v = __uint_as_float((unsigned int)(key >> 32));
        const int bk = bucket_of(v);
        if ((unsigned int)bk < bs || bk < LO_BIN) continue;
        const unsigned int l = atomicAdd(&off[bk - LO_BIN], 1u);
        const unsigned int pos = SA[b * NB + bk] + cnt[bk - LO_BIN] + l;
        if (pos < CAND_CAP) cb[pos] = key;
    }
}

// ---------------- K4: exact rank within bucket + per-keypoint outputs ----------------
__global__ __launch_bounds__(256) void k_out(
    const float* __restrict__ scores,
    const unsigned long long* __restrict__ cands,
    const unsigned int* __restrict__ ncand,
    const unsigned int* __restrict__ SA,
    const unsigned int* __restrict__ hist,
    float* __restrict__ out)
{
    const int b = blockIdx.y;
    unsigned int n = ncand[b];
    if (n > CAND_CAP) n = CAND_CAP;
    const int base = blockIdx.x * 256;
    const unsigned long long* cb = cands + (size_t)b * CAND_CAP;

    __shared__ unsigned long long seg[1024];
    for (int t = threadIdx.x; t < 1024; t += 256) {
        int gi = base - 384 + t;
        unsigned long long v = 0ull;
        if (gi >= 0 && gi < (int)n) v = cb[gi];
        seg[t] = v;
    }
    __syncthreads();

    unsigned int ci = base + threadIdx.x;
    if (ci >= n) return;

    const unsigned long long key = cb[ci];
    float v = __uint_as_float((unsigned int)(key >> 32));
    const int bk = bucket_of(v);
    const unsigned int seg0 = SA[b * NB + bk];
    const unsigned int len = hist[b * NB + bk];

    unsigned int r = 0;
    if ((int)seg0 >= base - 384 && (int)(seg0 + len) <= base + 640) {
        const int s0 = (int)seg0 - (base - 384);
        for (unsigned int j = 0; j < len; ++j)
            r += (seg[s0 + j] > key) ? 1u : 0u;
    } else {
#pragma unroll 4
        for (unsigned int j = 0; j < len; ++j)
            r += (cb[seg0 + j] > key) ? 1u : 0u;
    }
    const unsigned int rank = seg0 + r;
    if (rank >= TOPK) return;

    const unsigned int idx = ~((unsigned int)(key & 0xFFFFFFFFull));
    const int ky = (int)(idx >> 11);
    const int kx = (int)(idx & (WW - 1));
    const float* img = scores + (size_t)b * NPIX;

    float patch[25];
#pragma unroll
    for (int dy = 0; dy < 5; ++dy) {
#pragma unroll
        for (int dx = 0; dx < 5; ++dx) {
            patch[dy * 5 + dx] = img[(size_t)(ky + dy - 2) * WW + (kx + dx - 2)];
        }
    }
    float mx = patch[0];
#pragma unroll
    for (int p = 1; p < 25; ++p) mx = fmaxf(mx, patch[p]);

    float e[25];
    float s = 0.0f, sx = 0.0f, sy = 0.0f;
#pragma unroll
    for (int p = 0; p < 25; ++p) {
        float ex = expf((patch[p] - mx) * 10.0f);
        e[p] = ex;
        s += ex;
        sx += ex * (float)(p % 5 - 2);
        sy += ex * (float)(p / 5 - 2);
    }
    const float xx = sx / s;
    const float yy = sy / s;

    float dsum = 0.0f;
#pragma unroll
    for (int p = 0; p < 25; ++p) {
        float ddx = ((float)(p % 5 - 2) - xx) * 0.5f;
        float ddy = ((float)(p / 5 - 2) - yy) * 0.5f;
        dsum += e[p] * (ddx * ddx + ddy * ddy);
    }
    const float disp = dsum / s;

    const float kxy_x = ((float)kx + xx) / (float)(WW - 1) * 2.0f - 1.0f;
    const float kxy_y = ((float)ky + yy) / (float)(HH - 1) * 2.0f - 1.0f;

    const float px = (kxy_x + 1.0f) * 0.5f * (float)(WW - 1);
    const float py = (kxy_y + 1.0f) * 0.5f * (float)(HH - 1);
    int x0 = (int)floorf(px); x0 = x0 < 0 ? 0 : (x0 > WW - 1 ? WW - 1 : x0);
    int y0 = (int)floorf(py); y0 = y0 < 0 ? 0 : (y0 > HH - 1 ? HH - 1 : y0);
    int x1 = x0 + 1 > WW - 1 ? WW - 1 : x0 + 1;
    int y1 = y0 + 1 > HH - 1 ? HH - 1 : y0 + 1;
    const float wx = px - (float)x0;
    const float wy = py - (float)y0;
    const float v00 = img[(size_t)y0 * WW + x0];
    const float v01 = img[(size_t)y0 * WW + x1];
    const float v10 = img[(size_t)y1 * WW + x0];
    const float v11 = img[(size_t)y1 * WW + x1];
    const float ksc = v00 * (1.0f - wx) * (1.0f - wy) + v01 * wx * (1.0f - wy)
                    + v10 * (1.0f - wx) * wy + v11 * wx * wy;

    const size_t ok = (size_t)b * TOPK + rank;
    out[2 * ok]     = kxy_x;
    out[2 * ok + 1] = kxy_y;
    out[(size_t)BATCH * TOPK * 2 + ok] = ksc;
    out[(size_t)BATCH * TOPK * 3 + ok] = disp;
}

extern "C" void kernel_launch(void* const* d_in, const int* in_sizes, int n_in,
                              void* d_out, int out_size, void* d_ws, size_t ws_size,
                              hipStream_t stream) {
    const float* scores = (const float*)d_in[0];
    float* out = (float*)d_out;
    char* ws = (char*)d_ws;

    unsigned long long* peaks = (unsigned long long*)(ws + OFF_PEAKS);
    unsigned long long* cands = (unsigned long long*)(ws + OFF_CANDS);
    unsigned int* hist   = (unsigned int*)(ws + OFF_HIST);
    unsigned int* SA     = (unsigned int*)(ws + OFF_SA);
    unsigned int* fill   = (unsigned int*)(ws + OFF_FILL);
    unsigned int* pcount = (unsigned int*)(ws + OFF_PCOUNT);
    unsigned int* ncand  = (unsigned int*)(ws + OFF_NCAND);
    unsigned int* bstar  = (unsigned int*)(ws + OFF_BSTAR);

    // one contiguous zero: hist + SA + fill + counters
    hipMemsetAsync(ws + OFF_HIST, 0, (size_t)(OFF_END - OFF_HIST), stream);

    k_nms<<<dim3(WW / NMS_TW, HH / NMS_TH, BATCH), 512, 0, stream>>>(scores, peaks, pcount, hist);
    k_scan<<<dim3(BATCH), 256, 0, stream>>>(hist, SA, ncand, bstar);
    k_filter<<<dim3(PEAK_CAP / FCHUNK, BATCH), 256, 0, stream>>>(peaks, pcount, bstar, SA, fill, cands);
    k_out<<<dim3(CAND_CAP / 256, BATCH), 256, 0, stream>>>(scores, cands, ncand, SA, hist, out);
}

// Round 3
// 492.682 us; speedup vs baseline: 1.0138x; 1.0138x over previous
//
#include <hip/hip_runtime.h>

#define BATCH 8
#define HH 2048
#define WW 2048
#define NPIX (HH*WW)
#define TOPK 8192
#define NB 16384
#define PEAK_CAP 196608
#define FCHUNK 8192
#define LBINS 2048
#define LO_BIN (NB - LBINS)
#define CAND_CAP 16384

// workspace byte offsets (HIST->SA->FILL->counters contiguous for one memset)
#define OFF_PEAKS  0ull
#define OFF_CANDS  (OFF_PEAKS + (size_t)BATCH*PEAK_CAP*8ull)
#define OFF_HIST   (OFF_CANDS + (size_t)BATCH*CAND_CAP*8ull)
#define OFF_SA     (OFF_HIST  + (size_t)BATCH*NB*4ull)
#define OFF_FILL   (OFF_SA    + (size_t)BATCH*NB*4ull)
#define OFF_PCOUNT (OFF_FILL  + (size_t)BATCH*NB*4ull)
#define OFF_NCAND  (OFF_PCOUNT + 64ull)
#define OFF_BSTAR  (OFF_NCAND + 64ull)
#define OFF_END    (OFF_PCOUNT + 192ull)

__device__ __forceinline__ int bucket_of(float v) {
    int bk = (int)(v * 16384.0f);
    if (bk > NB - 1) bk = NB - 1;
    if (bk < 0) bk = 0;
    return bk;
}

// ---------------- K1: NMS, register-direct with deep MLP ----------------
// Block 256 threads as 16x16; each thread: 4 cols x 4 rows. All 24 float4
// loads issued in one unrolled pass into A/B/C register arrays (launch_bounds
// (256,4) licenses ~128 VGPR so they stay in flight), then compute.
// Fused: value histogram built during the peak drain (no separate k_hist).
__global__ __launch_bounds__(256, 4) void k_nms(
    const float* __restrict__ scores,
    unsigned long long* __restrict__ peaks,
    unsigned int* __restrict__ pcount,
    unsigned int* __restrict__ hist)
{
    const int b = blockIdx.z;
    const int tx = threadIdx.x & 15;
    const int ty = threadIdx.x >> 4;
    const int x = blockIdx.x * 64 + tx * 4;
    const int y = blockIdx.y * 64 + ty * 4;
    const float* img = scores + (size_t)b * NPIX;
    const float4* imgq = (const float4*)img;

    __shared__ unsigned long long lbuf[512];
    __shared__ unsigned int lcnt;
    __shared__ unsigned int lbase;
    if (threadIdx.x == 0) lcnt = 0;
    __syncthreads();

    const int q = x >> 2;
    const int qm = (q > 0) ? q - 1 : 0;
    const int qp = (q < WW / 4 - 1) ? q + 1 : WW / 4 - 1;

    // ---- pass 1: issue all 24 independent loads ----
    float4 A[8], B[8], C[8];
#pragma unroll
    for (int j = 0; j < 8; ++j) {
        int gy = y - 2 + j;
        gy = gy < 0 ? 0 : (gy > HH - 1 ? HH - 1 : gy);
        const float4* rowq = imgq + (size_t)gy * (WW / 4);
        A[j] = rowq[qm];
        B[j] = rowq[q];
        C[j] = rowq[qp];
    }

    // ---- pass 2: horizontal 5-max per row, center values ----
    float hm[8][4];
    float c4[4][4];
#pragma unroll
    for (int j = 0; j < 8; ++j) {
        const float v[12] = {A[j].x, A[j].y, A[j].z, A[j].w,
                             B[j].x, B[j].y, B[j].z, B[j].w,
                             C[j].x, C[j].y, C[j].z, C[j].w};
        float aa[8];
#pragma unroll
        for (int k = 0; k < 8; ++k) aa[k] = fmaxf(v[k + 2], v[k + 3]);
#pragma unroll
        for (int i = 0; i < 4; ++i)
            hm[j][i] = fmaxf(fmaxf(aa[i], aa[i + 2]), v[i + 6]);
        if (j >= 2 && j <= 5) {
#pragma unroll
            for (int i = 0; i < 4; ++i) c4[j - 2][i] = v[i + 4];
        }
    }

    // ---- vertical 5-max + peak test ----
#pragma unroll
    for (int r = 0; r < 4; ++r) {
        const int oy = y + r;
        const bool yok = (oy >= 2) && (oy <= HH - 3);
#pragma unroll
        for (int i = 0; i < 4; ++i) {
            const float vm = fmaxf(fmaxf(fmaxf(hm[r][i], hm[r + 1][i]),
                                         fmaxf(hm[r + 2][i], hm[r + 3][i])),
                                   hm[r + 4][i]);
            const float cv = c4[r][i];
            const int col = x + i;
            if (yok && col >= 2 && col <= WW - 3 && cv == vm) {
                unsigned int pos = atomicAdd(&lcnt, 1u);
                if (pos < 512u) {
                    unsigned int idx = (unsigned int)(oy * WW + col);
                    lbuf[pos] = ((unsigned long long)__float_as_uint(cv) << 32) |
                                (unsigned long long)(~idx);
                }
            }
        }
    }
    __syncthreads();

    unsigned int cnt = lcnt;
    if (cnt > 512u) cnt = 512u;
    if (threadIdx.x == 0) lbase = atomicAdd(&pcount[b], cnt);
    __syncthreads();
    const unsigned int gbase = lbase;
    for (unsigned int s = threadIdx.x; s < cnt; s += 256) {
        const unsigned long long key = lbuf[s];
        const unsigned int gpos = gbase + s;
        if (gpos < PEAK_CAP) peaks[(size_t)b * PEAK_CAP + gpos] = key;
        const float v = __uint_as_float((unsigned int)(key >> 32));
        atomicAdd(&hist[(size_t)b * NB + bucket_of(v)], 1u);   // fused k_hist
    }
}

// ---------------- K2: suffix scan over global hist ----------------
// grid: (8), block 256. Histogram comes straight from k_nms atomics.
__global__ __launch_bounds__(256) void k_scan(
    const unsigned int* __restrict__ hist,
    unsigned int* __restrict__ SA,
    unsigned int* __restrict__ ncand,
    unsigned int* __restrict__ bstar)
{
    const int b = blockIdx.x;
    unsigned int* sab = SA + b * NB;
    const int t = threadIdx.x;

    __shared__ unsigned int h[NB / 2];   // packed lo | hi<<16, 32 KB
    __shared__ unsigned int ps[256];
    __shared__ int bmax;

    const uint2* hb = (const uint2*)(hist + (size_t)b * NB);
    for (int w = t; w < NB / 2; w += 256) {
        const uint2 p = hb[w];
        h[w] = p.x | (p.y << 16);        // counts < 65536
    }
    __syncthreads();

    // per-thread 64-bin total; rotated index -> conflict-free LDS
    unsigned int sum = 0;
    for (int kk = 0; kk < 32; ++kk) {
        const int k = (kk + t) & 31;
        const unsigned int p = h[t * 32 + k];
        sum += (p & 0xFFFFu) + (p >> 16);
    }
    ps[t] = sum;
    __syncthreads();
    for (int off = 1; off < 256; off <<= 1) {
        unsigned int v = (t + off < 256) ? ps[t + off] : 0u;
        __syncthreads();
        ps[t] += v;
        __syncthreads();
    }
    unsigned int run = ps[t] - sum;  // strictly above this thread's chunk
    int bst_local = -1;
    for (int i = 63; i >= 0; --i) {
        const int bin = t * 64 + i;
        const unsigned int w = h[t * 32 + (i >> 1)];
        const unsigned int hv = (i & 1) ? (w >> 16) : (w & 0xFFFFu);
        sab[bin] = run;
        if (run + hv >= TOPK && bst_local < 0) bst_local = bin;
        run += hv;
    }
    if (t == 0) bmax = -1;
    __syncthreads();
    if (bst_local >= 0) atomicMax(&bmax, bst_local);
    __syncthreads();
    if (t == 0) {
        const int Bs = bmax < 0 ? 0 : bmax;
        bstar[b] = (unsigned int)Bs;
        const unsigned int w = h[Bs >> 1];
        const unsigned int hv = (Bs & 1) ? (w >> 16) : (w & 0xFFFFu);
        unsigned int nc = sab[Bs] + hv;
        if (nc > CAND_CAP) nc = CAND_CAP;
        ncand[b] = nc;
    }
}

// ---------------- K3: filter -> bucket-grouped cands, aggregated atomics ----------------
__global__ __launch_bounds__(256) void k_filter(
    const unsigned long long* __restrict__ peaks,
    const unsigned int* __restrict__ pcount,
    const unsigned int* __restrict__ bstar,
    const unsigned int* __restrict__ SA,
    unsigned int* __restrict__ fill,
    unsigned long long* __restrict__ cands)
{
    const int b = blockIdx.y;
    unsigned int n = pcount[b];
    if (n > PEAK_CAP) n = PEAK_CAP;
    const unsigned int base = blockIdx.x * FCHUNK;
    if (base >= n) return;
    const unsigned int end = (base + FCHUNK < n) ? base + FCHUNK : n;
    const unsigned int bs = bstar[b];
    const unsigned long long* pb = peaks + (size_t)b * PEAK_CAP;
    unsigned long long* cb = cands + (size_t)b * CAND_CAP;

    __shared__ unsigned int cnt[LBINS];
    __shared__ unsigned int off[LBINS];
    for (int j = threadIdx.x; j < LBINS; j += 256) { cnt[j] = 0u; off[j] = 0u; }
    __syncthreads();

    for (unsigned int i = base + threadIdx.x; i < end; i += 256) {
        const unsigned long long key = pb[i];
        const float v = __uint_as_float((unsigned int)(key >> 32));
        const int bk = bucket_of(v);
        if ((unsigned int)bk < bs) continue;
        if (bk >= LO_BIN) {
            atomicAdd(&cnt[bk - LO_BIN], 1u);
        } else {
            unsigned int pos = SA[b * NB + bk] + atomicAdd(&fill[b * NB + bk], 1u);
            if (pos < CAND_CAP) cb[pos] = key;
        }
    }
    __syncthreads();

    for (int j = threadIdx.x; j < LBINS; j += 256) {
        const unsigned int c = cnt[j];
        if (c) cnt[j] = atomicAdd(&fill[b * NB + LO_BIN + j], c);
    }
    __syncthreads();

    for (unsigned int i = base + threadIdx.x; i < end; i += 256) {
        const unsigned long long key = pb[i];
        const float v = __uint_as_float((unsigned int)(key >> 32));
        const int bk = bucket_of(v);
        if ((unsigned int)bk < bs || bk < LO_BIN) continue;
        const unsigned int l = atomicAdd(&off[bk - LO_BIN], 1u);
        const unsigned int pos = SA[b * NB + bk] + cnt[bk - LO_BIN] + l;
        if (pos < CAND_CAP) cb[pos] = key;
    }
}

// ---------------- K4: exact rank within bucket + per-keypoint outputs ----------------
__global__ __launch_bounds__(256) void k_out(
    const float* __restrict__ scores,
    const unsigned long long* __restrict__ cands,
    const unsigned int* __restrict__ ncand,
    const unsigned int* __restrict__ SA,
    const unsigned int* __restrict__ hist,
    float* __restrict__ out)
{
    const int b = blockIdx.y;
    unsigned int n = ncand[b];
    if (n > CAND_CAP) n = CAND_CAP;
    const int base = blockIdx.x * 256;
    const unsigned long long* cb = cands + (size_t)b * CAND_CAP;

    __shared__ unsigned long long seg[1024];
    for (int t = threadIdx.x; t < 1024; t += 256) {
        int gi = base - 384 + t;
        unsigned long long v = 0ull;
        if (gi >= 0 && gi < (int)n) v = cb[gi];
        seg[t] = v;
    }
    __syncthreads();

    unsigned int ci = base + threadIdx.x;
    if (ci >= n) return;

    const unsigned long long key = cb[ci];
    float v = __uint_as_float((unsigned int)(key >> 32));
    const int bk = bucket_of(v);
    const unsigned int seg0 = SA[b * NB + bk];
    const unsigned int len = hist[b * NB + bk];

    unsigned int r = 0;
    if ((int)seg0 >= base - 384 && (int)(seg0 + len) <= base + 640) {
        const int s0 = (int)seg0 - (base - 384);
        for (unsigned int j = 0; j < len; ++j)
            r += (seg[s0 + j] > key) ? 1u : 0u;
    } else {
#pragma unroll 4
        for (unsigned int j = 0; j < len; ++j)
            r += (cb[seg0 + j] > key) ? 1u : 0u;
    }
    const unsigned int rank = seg0 + r;
    if (rank >= TOPK) return;

    const unsigned int idx = ~((unsigned int)(key & 0xFFFFFFFFull));
    const int ky = (int)(idx >> 11);
    const int kx = (int)(idx & (WW - 1));
    const float* img = scores + (size_t)b * NPIX;

    float patch[25];
#pragma unroll
    for (int dy = 0; dy < 5; ++dy) {
#pragma unroll
        for (int dx = 0; dx < 5; ++dx) {
            patch[dy * 5 + dx] = img[(size_t)(ky + dy - 2) * WW + (kx + dx - 2)];
        }
    }
    float mx = patch[0];
#pragma unroll
    for (int p = 1; p < 25; ++p) mx = fmaxf(mx, patch[p]);

    float e[25];
    float s = 0.0f, sx = 0.0f, sy = 0.0f;
#pragma unroll
    for (int p = 0; p < 25; ++p) {
        float ex = expf((patch[p] - mx) * 10.0f);
        e[p] = ex;
        s += ex;
        sx += ex * (float)(p % 5 - 2);
        sy += ex * (float)(p / 5 - 2);
    }
    const float xx = sx / s;
    const float yy = sy / s;

    float dsum = 0.0f;
#pragma unroll
    for (int p = 0; p < 25; ++p) {
        float ddx = ((float)(p % 5 - 2) - xx) * 0.5f;
        float ddy = ((float)(p / 5 - 2) - yy) * 0.5f;
        dsum += e[p] * (ddx * ddx + ddy * ddy);
    }
    const float disp = dsum / s;

    const float kxy_x = ((float)kx + xx) / (float)(WW - 1) * 2.0f - 1.0f;
    const float kxy_y = ((float)ky + yy) / (float)(HH - 1) * 2.0f - 1.0f;

    const float px = (kxy_x + 1.0f) * 0.5f * (float)(WW - 1);
    const float py = (kxy_y + 1.0f) * 0.5f * (float)(HH - 1);
    int x0 = (int)floorf(px); x0 = x0 < 0 ? 0 : (x0 > WW - 1 ? WW - 1 : x0);
    int y0 = (int)floorf(py); y0 = y0 < 0 ? 0 : (y0 > HH - 1 ? HH - 1 : y0);
    int x1 = x0 + 1 > WW - 1 ? WW - 1 : x0 + 1;
    int y1 = y0 + 1 > HH - 1 ? HH - 1 : y0 + 1;
    const float wx = px - (float)x0;
    const float wy = py - (float)y0;
    const float v00 = img[(size_t)y0 * WW + x0];
    const float v01 = img[(size_t)y0 * WW + x1];
    const float v10 = img[(size_t)y1 * WW + x0];
    const float v11 = img[(size_t)y1 * WW + x1];
    const float ksc = v00 * (1.0f - wx) * (1.0f - wy) + v01 * wx * (1.0f - wy)
                    + v10 * (1.0f - wx) * wy + v11 * wx * wy;

    const size_t ok = (size_t)b * TOPK + rank;
    out[2 * ok]     = kxy_x;
    out[2 * ok + 1] = kxy_y;
    out[(size_t)BATCH * TOPK * 2 + ok] = ksc;
    out[(size_t)BATCH * TOPK * 3 + ok] = disp;
}

extern "C" void kernel_launch(void* const* d_in, const int* in_sizes, int n_in,
                              void* d_out, int out_size, void* d_ws, size_t ws_size,
                              hipStream_t stream) {
    const float* scores = (const float*)d_in[0];
    float* out = (float*)d_out;
    char* ws = (char*)d_ws;

    unsigned long long* peaks = (unsigned long long*)(ws + OFF_PEAKS);
    unsigned long long* cands = (unsigned long long*)(ws + OFF_CANDS);
    unsigned int* hist   = (unsigned int*)(ws + OFF_HIST);
    unsigned int* SA     = (unsigned int*)(ws + OFF_SA);
    unsigned int* fill   = (unsigned int*)(ws + OFF_FILL);
    unsigned int* pcount = (unsigned int*)(ws + OFF_PCOUNT);
    unsigned int* ncand  = (unsigned int*)(ws + OFF_NCAND);
    unsigned int* bstar  = (unsigned int*)(ws + OFF_BSTAR);

    // one contiguous zero: hist + SA + fill + counters
    hipMemsetAsync(ws + OFF_HIST, 0, (size_t)(OFF_END - OFF_HIST), stream);

    k_nms<<<dim3(WW / 64, HH / 64, BATCH), 256, 0, stream>>>(scores, peaks, pcount, hist);
    k_scan<<<dim3(BATCH), 256, 0, stream>>>(hist, SA, ncand, bstar);
    k_filter<<<dim3(PEAK_CAP / FCHUNK, BATCH), 256, 0, stream>>>(peaks, pcount, bstar, SA, fill, cands);
    k_out<<<dim3(CAND_CAP / 256, BATCH), 256, 0, stream>>>(scores, cands, ncand, SA, hist, out);
}

// Round 5
// 480.036 us; speedup vs baseline: 1.0405x; 1.0263x over previous
//
#include <hip/hip_runtime.h>

#define BATCH 8
#define HH 2048
#define WW 2048
#define NPIX (HH*WW)
#define TOPK 8192
#define NB 16384
#define PEAK_CAP 196608
#define FCHUNK 8192
#define LBINS 2048
#define LO_BIN (NB - LBINS)
#define CAND_CAP 16384

// workspace byte offsets (HIST->SA->FILL->counters contiguous for one memset)
#define OFF_PEAKS  0ull
#define OFF_CANDS  (OFF_PEAKS + (size_t)BATCH*PEAK_CAP*8ull)
#define OFF_HIST   (OFF_CANDS + (size_t)BATCH*CAND_CAP*8ull)
#define OFF_SA     (OFF_HIST  + (size_t)BATCH*NB*4ull)
#define OFF_FILL   (OFF_SA    + (size_t)BATCH*NB*4ull)
#define OFF_PCOUNT (OFF_FILL  + (size_t)BATCH*NB*4ull)
#define OFF_NCAND  (OFF_PCOUNT + 64ull)
#define OFF_BSTAR  (OFF_NCAND + 64ull)
#define OFF_END    (OFF_PCOUNT + 192ull)

__device__ __forceinline__ int bucket_of(float v) {
    int bk = (int)(v * 16384.0f);
    if (bk > NB - 1) bk = NB - 1;
    if (bk < 0) bk = 0;
    return bk;
}

// ---------------- K1: NMS via wave-wide shuffle neighbor exchange ----------------
// Block 256 = 4 waves; wave w covers a 256x4 output strip (tile 256x16).
// Lane l owns quad q0+l. Per wave: 8 own-row float4 loads + 1 combined halo
// load (lanes 0-7 left halo rows 0-7, lanes 8-15 right) instead of 24 loads.
// Column neighbors via __shfl_up/down; lane 0/63 patched from halo quad.
// Vertical 5-max accumulated incrementally (vm[4][4], no hm[8][4]).
// Fused: value histogram built during the peak drain.
__global__ __launch_bounds__(256) void k_nms(
    const float* __restrict__ scores,
    unsigned long long* __restrict__ peaks,
    unsigned int* __restrict__ pcount,
    unsigned int* __restrict__ hist)
{
    const int b = blockIdx.z;
    const int tid = threadIdx.x;
    const int lane = tid & 63;
    const int wv = tid >> 6;                    // wave id 0..3
    const int x0 = blockIdx.x * 256;
    const int yb = blockIdx.y * 16 + wv * 4;    // first output row of this wave
    const float4* imgq = (const float4*)(scores + (size_t)b * NPIX);
    const int q0 = x0 >> 2;
    const int qb = q0 + lane;

    __shared__ unsigned long long lbuf[768];
    __shared__ unsigned int lcnt;
    __shared__ unsigned int lbase;
    if (tid == 0) lcnt = 0;
    __syncthreads();

    // halo quad: lanes 0-7 carry left-halo rows 0..7, lanes 8-15 right-halo.
    const int hj = lane & 7;
    int hgy = yb - 2 + hj;
    hgy = hgy < 0 ? 0 : (hgy > HH - 1 ? HH - 1 : hgy);
    const int qL = q0 > 0 ? q0 - 1 : 0;
    const int qR = (q0 + 64 < WW / 4) ? q0 + 64 : WW / 4 - 1;
    const int hq = ((lane & 8) == 0) ? qL : qR;
    const float4 h4 = imgq[(size_t)hgy * (WW / 4) + hq];

    // own 8 rows (all independent, in flight together)
    float4 bq[8];
#pragma unroll
    for (int j = 0; j < 8; ++j) {
        int gy = yb - 2 + j;
        gy = gy < 0 ? 0 : (gy > HH - 1 ? HH - 1 : gy);
        bq[j] = imgq[(size_t)gy * (WW / 4) + qb];
    }

    float vm[4][4];   // vertical 5-max accumulators for 4 output rows
    float c4[4][4];   // center values
#pragma unroll
    for (int j = 0; j < 8; ++j) {
        float v0 = __shfl_up(bq[j].z, 1);
        float v1 = __shfl_up(bq[j].w, 1);
        float v6 = __shfl_down(bq[j].x, 1);
        float v7 = __shfl_down(bq[j].y, 1);
        const float hlz = __shfl(h4.z, j);       // left halo col x0-2, row j
        const float hlw = __shfl(h4.w, j);       // left halo col x0-1
        const float hrx = __shfl(h4.x, 8 + j);   // right halo col x0+256
        const float hry = __shfl(h4.y, 8 + j);   // right halo col x0+257
        if (lane == 0)  { v0 = hlz; v1 = hlw; }
        if (lane == 63) { v6 = hrx; v7 = hry; }
        // window cols c-2 .. c+5 for this lane (c = x0 + lane*4)
        const float w8[8] = {v0, v1, bq[j].x, bq[j].y, bq[j].z, bq[j].w, v6, v7};
        float p[7];
#pragma unroll
        for (int k = 0; k < 7; ++k) p[k] = fmaxf(w8[k], w8[k + 1]);
        float hmj[4];
#pragma unroll
        for (int i = 0; i < 4; ++i)
            hmj[i] = fmaxf(fmaxf(p[i], p[i + 2]), w8[i + 4]);
        if (j >= 2 && j <= 5) {
#pragma unroll
            for (int i = 0; i < 4; ++i) c4[j - 2][i] = w8[i + 2];
        }
#pragma unroll
        for (int r = 0; r < 4; ++r) {
            if (j == r) {
#pragma unroll
                for (int i = 0; i < 4; ++i) vm[r][i] = hmj[i];
            } else if (j > r && j <= r + 4) {
#pragma unroll
                for (int i = 0; i < 4; ++i) vm[r][i] = fmaxf(vm[r][i], hmj[i]);
            }
        }
    }

    // peak test + local buffer
#pragma unroll
    for (int r = 0; r < 4; ++r) {
        const int oy = yb + r;
        const bool yok = (oy >= 2) && (oy <= HH - 3);
#pragma unroll
        for (int i = 0; i < 4; ++i) {
            const float cv = c4[r][i];
            const int col = x0 + lane * 4 + i;
            if (yok && col >= 2 && col <= WW - 3 && cv == vm[r][i]) {
                unsigned int pos = atomicAdd(&lcnt, 1u);
                if (pos < 768u) {
                    unsigned int idx = (unsigned int)(oy * WW + col);
                    lbuf[pos] = ((unsigned long long)__float_as_uint(cv) << 32) |
                                (unsigned long long)(~idx);
                }
            }
        }
    }
    __syncthreads();

    unsigned int cnt = lcnt;
    if (cnt > 768u) cnt = 768u;
    if (tid == 0) lbase = atomicAdd(&pcount[b], cnt);
    __syncthreads();
    const unsigned int gbase = lbase;
    for (unsigned int s = tid; s < cnt; s += 256) {
        const unsigned long long key = lbuf[s];
        const unsigned int gpos = gbase + s;
        if (gpos < PEAK_CAP) peaks[(size_t)b * PEAK_CAP + gpos] = key;
        const float v = __uint_as_float((unsigned int)(key >> 32));
        atomicAdd(&hist[(size_t)b * NB + bucket_of(v)], 1u);   // fused k_hist
    }
}

// ---------------- K2: suffix scan over global hist ----------------
__global__ __launch_bounds__(256) void k_scan(
    const unsigned int* __restrict__ hist,
    unsigned int* __restrict__ SA,
    unsigned int* __restrict__ ncand,
    unsigned int* __restrict__ bstar)
{
    const int b = blockIdx.x;
    unsigned int* sab = SA + b * NB;
    const int t = threadIdx.x;

    __shared__ unsigned int h[NB / 2];   // packed lo | hi<<16, 32 KB
    __shared__ unsigned int ps[256];
    __shared__ int bmax;

    const uint2* hb = (const uint2*)(hist + (size_t)b * NB);
    for (int w = t; w < NB / 2; w += 256) {
        const uint2 p = hb[w];
        h[w] = p.x | (p.y << 16);        // counts < 65536
    }
    __syncthreads();

    unsigned int sum = 0;
    for (int kk = 0; kk < 32; ++kk) {
        const int k = (kk + t) & 31;
        const unsigned int p = h[t * 32 + k];
        sum += (p & 0xFFFFu) + (p >> 16);
    }
    ps[t] = sum;
    __syncthreads();
    for (int off = 1; off < 256; off <<= 1) {
        unsigned int v = (t + off < 256) ? ps[t + off] : 0u;
        __syncthreads();
        ps[t] += v;
        __syncthreads();
    }
    unsigned int run = ps[t] - sum;
    int bst_local = -1;
    for (int i = 63; i >= 0; --i) {
        const int bin = t * 64 + i;
        const unsigned int w = h[t * 32 + (i >> 1)];
        const unsigned int hv = (i & 1) ? (w >> 16) : (w & 0xFFFFu);
        sab[bin] = run;
        if (run + hv >= TOPK && bst_local < 0) bst_local = bin;
        run += hv;
    }
    if (t == 0) bmax = -1;
    __syncthreads();
    if (bst_local >= 0) atomicMax(&bmax, bst_local);
    __syncthreads();
    if (t == 0) {
        const int Bs = bmax < 0 ? 0 : bmax;
        bstar[b] = (unsigned int)Bs;
        const unsigned int w = h[Bs >> 1];
        const unsigned int hv = (Bs & 1) ? (w >> 16) : (w & 0xFFFFu);
        unsigned int nc = sab[Bs] + hv;
        if (nc > CAND_CAP) nc = CAND_CAP;
        ncand[b] = nc;
    }
}

// ---------------- K3: filter -> bucket-grouped cands, aggregated atomics ----------------
__global__ __launch_bounds__(256) void k_filter(
    const unsigned long long* __restrict__ peaks,
    const unsigned int* __restrict__ pcount,
    const unsigned int* __restrict__ bstar,
    const unsigned int* __restrict__ SA,
    unsigned int* __restrict__ fill,
    unsigned long long* __restrict__ cands)
{
    const int b = blockIdx.y;
    unsigned int n = pcount[b];
    if (n > PEAK_CAP) n = PEAK_CAP;
    const unsigned int base = blockIdx.x * FCHUNK;
    if (base >= n) return;
    const unsigned int end = (base + FCHUNK < n) ? base + FCHUNK : n;
    const unsigned int bs = bstar[b];
    const unsigned long long* pb = peaks + (size_t)b * PEAK_CAP;
    unsigned long long* cb = cands + (size_t)b * CAND_CAP;

    __shared__ unsigned int cnt[LBINS];
    __shared__ unsigned int off[LBINS];
    for (int j = threadIdx.x; j < LBINS; j += 256) { cnt[j] = 0u; off[j] = 0u; }
    __syncthreads();

    for (unsigned int i = base + threadIdx.x; i < end; i += 256) {
        const unsigned long long key = pb[i];
        const float v = __uint_as_float((unsigned int)(key >> 32));
        const int bk = bucket_of(v);
        if ((unsigned int)bk < bs) continue;
        if (bk >= LO_BIN) {
            atomicAdd(&cnt[bk - LO_BIN], 1u);
        } else {
            unsigned int pos = SA[b * NB + bk] + atomicAdd(&fill[b * NB + bk], 1u);
            if (pos < CAND_CAP) cb[pos] = key;
        }
    }
    __syncthreads();

    for (int j = threadIdx.x; j < LBINS; j += 256) {
        const unsigned int c = cnt[j];
        if (c) cnt[j] = atomicAdd(&fill[b * NB + LO_BIN + j], c);
    }
    __syncthreads();

    for (unsigned int i = base + threadIdx.x; i < end; i += 256) {
        const unsigned long long key = pb[i];
        const float v = __uint_as_float((unsigned int)(key >> 32));
        const int bk = bucket_of(v);
        if ((unsigned int)bk < bs || bk < LO_BIN) continue;
        const unsigned int l = atomicAdd(&off[bk - LO_BIN], 1u);
        const unsigned int pos = SA[b * NB + bk] + cnt[bk - LO_BIN] + l;
        if (pos < CAND_CAP) cb[pos] = key;
    }
}

// ---------------- K4: exact rank within bucket + per-keypoint outputs ----------------
__global__ __launch_bounds__(256) void k_out(
    const float* __restrict__ scores,
    const unsigned long long* __restrict__ cands,
    const unsigned int* __restrict__ ncand,
    const unsigned int* __restrict__ SA,
    const unsigned int* __restrict__ hist,
    float* __restrict__ out)
{
    const int b = blockIdx.y;
    unsigned int n = ncand[b];
    if (n > CAND_CAP) n = CAND_CAP;
    const int base = blockIdx.x * 256;
    const unsigned long long* cb = cands + (size_t)b * CAND_CAP;

    __shared__ unsigned long long seg[1024];
    for (int t = threadIdx.x; t < 1024; t += 256) {
        int gi = base - 384 + t;
        unsigned long long v = 0ull;
        if (gi >= 0 && gi < (int)n) v = cb[gi];
        seg[t] = v;
    }
    __syncthreads();

    unsigned int ci = base + threadIdx.x;
    if (ci >= n) return;

    const unsigned long long key = cb[ci];
    float v = __uint_as_float((unsigned int)(key >> 32));
    const int bk = bucket_of(v);
    const unsigned int seg0 = SA[b * NB + bk];
    const unsigned int len = hist[b * NB + bk];

    unsigned int r = 0;
    if ((int)seg0 >= base - 384 && (int)(seg0 + len) <= base + 640) {
        const int s0 = (int)seg0 - (base - 384);
        for (unsigned int j = 0; j < len; ++j)
            r += (seg[s0 + j] > key) ? 1u : 0u;
    } else {
#pragma unroll 4
        for (unsigned int j = 0; j < len; ++j)
            r += (cb[seg0 + j] > key) ? 1u : 0u;
    }
    const unsigned int rank = seg0 + r;
    if (rank >= TOPK) return;

    const unsigned int idx = ~((unsigned int)(key & 0xFFFFFFFFull));
    const int ky = (int)(idx >> 11);
    const int kx = (int)(idx & (WW - 1));
    const float* img = scores + (size_t)b * NPIX;

    float patch[25];
#pragma unroll
    for (int dy = 0; dy < 5; ++dy) {
#pragma unroll
        for (int dx = 0; dx < 5; ++dx) {
            patch[dy * 5 + dx] = img[(size_t)(ky + dy - 2) * WW + (kx + dx - 2)];
        }
    }
    float mx = patch[0];
#pragma unroll
    for (int p = 1; p < 25; ++p) mx = fmaxf(mx, patch[p]);

    float e[25];
    float s = 0.0f, sx = 0.0f, sy = 0.0f;
#pragma unroll
    for (int p = 0; p < 25; ++p) {
        float ex = expf((patch[p] - mx) * 10.0f);
        e[p] = ex;
        s += ex;
        sx += ex * (float)(p % 5 - 2);
        sy += ex * (float)(p / 5 - 2);
    }
    const float xx = sx / s;
    const float yy = sy / s;

    float dsum = 0.0f;
#pragma unroll
    for (int p = 0; p < 25; ++p) {
        float ddx = ((float)(p % 5 - 2) - xx) * 0.5f;
        float ddy = ((float)(p / 5 - 2) - yy) * 0.5f;
        dsum += e[p] * (ddx * ddx + ddy * ddy);
    }
    const float disp = dsum / s;

    const float kxy_x = ((float)kx + xx) / (float)(WW - 1) * 2.0f - 1.0f;
    const float kxy_y = ((float)ky + yy) / (float)(HH - 1) * 2.0f - 1.0f;

    const float px = (kxy_x + 1.0f) * 0.5f * (float)(WW - 1);
    const float py = (kxy_y + 1.0f) * 0.5f * (float)(HH - 1);
    int x0 = (int)floorf(px); x0 = x0 < 0 ? 0 : (x0 > WW - 1 ? WW - 1 : x0);
    int y0 = (int)floorf(py); y0 = y0 < 0 ? 0 : (y0 > HH - 1 ? HH - 1 : y0);
    int x1 = x0 + 1 > WW - 1 ? WW - 1 : x0 + 1;
    int y1 = y0 + 1 > HH - 1 ? HH - 1 : y0 + 1;
    const float wx = px - (float)x0;
    const float wy = py - (float)y0;
    const float v00 = img[(size_t)y0 * WW + x0];
    const float v01 = img[(size_t)y0 * WW + x1];
    const float v10 = img[(size_t)y1 * WW + x0];
    const float v11 = img[(size_t)y1 * WW + x1];
    const float ksc = v00 * (1.0f - wx) * (1.0f - wy) + v01 * wx * (1.0f - wy)
                    + v10 * (1.0f - wx) * wy + v11 * wx * wy;

    const size_t ok = (size_t)b * TOPK + rank;
    out[2 * ok]     = kxy_x;
    out[2 * ok + 1] = kxy_y;
    out[(size_t)BATCH * TOPK * 2 + ok] = ksc;
    out[(size_t)BATCH * TOPK * 3 + ok] = disp;
}

extern "C" void kernel_launch(void* const* d_in, const int* in_sizes, int n_in,
                              void* d_out, int out_size, void* d_ws, size_t ws_size,
                              hipStream_t stream) {
    const float* scores = (const float*)d_in[0];
    float* out = (float*)d_out;
    char* ws = (char*)d_ws;

    unsigned long long* peaks = (unsigned long long*)(ws + OFF_PEAKS);
    unsigned long long* cands = (unsigned long long*)(ws + OFF_CANDS);
    unsigned int* hist   = (unsigned int*)(ws + OFF_HIST);
    unsigned int* SA     = (unsigned int*)(ws + OFF_SA);
    unsigned int* fill   = (unsigned int*)(ws + OFF_FILL);
    unsigned int* pcount = (unsigned int*)(ws + OFF_PCOUNT);
    unsigned int* ncand  = (unsigned int*)(ws + OFF_NCAND);
    unsigned int* bstar  = (unsigned int*)(ws + OFF_BSTAR);

    // one contiguous zero: hist + SA + fill + counters
    hipMemsetAsync(ws + OFF_HIST, 0, (size_t)(OFF_END - OFF_HIST), stream);

    k_nms<<<dim3(WW / 256, HH / 16, BATCH), 256, 0, stream>>>(scores, peaks, pcount, hist);
    k_scan<<<dim3(BATCH), 256, 0, stream>>>(hist, SA, ncand, bstar);
    k_filter<<<dim3(PEAK_CAP / FCHUNK, BATCH), 256, 0, stream>>>(peaks, pcount, bstar, SA, fill, cands);
    k_out<<<dim3(CAND_CAP / 256, BATCH), 256, 0, stream>>>(scores, cands, ncand, SA, hist, out);
}